// Round 11
// baseline (360.104 us; speedup 1.0000x reference)
//
#include <hip/hip_runtime.h>

typedef __bf16 bf16_t;
typedef __bf16 bf16x4 __attribute__((ext_vector_type(4)));
typedef __bf16 bf16x8 __attribute__((ext_vector_type(8)));
typedef float f32x4 __attribute__((ext_vector_type(4)));
typedef float f32x16 __attribute__((ext_vector_type(16)));
typedef unsigned u32x2 __attribute__((ext_vector_type(2)));

#define QSCALE 0.18033688f  // 0.125 * log2(e)

// XOR swizzle of the 16B-slot index within a 128B LDS row (8 slots):
__device__ __forceinline__ int swz(int row) { return (row ^ (row >> 3)) & 7; }
// XOR swizzle for 64B rows (4 slots of 16B):
__device__ __forceinline__ int swz2(int row) { return (row ^ (row >> 2)) & 3; }

__device__ __forceinline__ f32x4 mfma16(bf16x8 a, bf16x8 b, f32x4 c) {
  return __builtin_amdgcn_mfma_f32_16x16x32_bf16(a, b, c, 0, 0, 0);
}
__device__ __forceinline__ f32x16 mfma32(bf16x8 a, bf16x8 b, f32x16 c) {
  return __builtin_amdgcn_mfma_f32_32x32x16_bf16(a, b, c, 0, 0, 0);
}

__device__ __forceinline__ void gl_lds16(const void* g, void* l) {
  __builtin_amdgcn_global_load_lds(
      (const __attribute__((address_space(1))) unsigned int*)g,
      (__attribute__((address_space(3))) unsigned int*)l, 16, 0, 0);
}

// ---------------------------------------------------------------------------
// Fused pre-pass (ONE launch): f32->bf16 for 3 inputs + 4 weights + mask pack.
// Wq is pre-scaled by QSCALE (softmax exp2-space fold).
// ---------------------------------------------------------------------------
__global__ __launch_bounds__(256) void cvt_all_kernel(
    const float* __restrict__ key, const float* __restrict__ query,
    const float* __restrict__ value, const float* __restrict__ Wk,
    const float* __restrict__ Wq, const float* __restrict__ Wv,
    const float* __restrict__ Wp, const int* __restrict__ mask,
    bf16_t* __restrict__ I1, bf16_t* __restrict__ I2, bf16_t* __restrict__ I3,
    bf16_t* __restrict__ Wkb, bf16_t* __restrict__ Wqb,
    bf16_t* __restrict__ Wvb, bf16_t* __restrict__ Wpb,
    unsigned* __restrict__ mbits) {
  const int bid = blockIdx.x;
  if (bid >= 53248) {  // mask pack
    int idx = (bid - 53248) * 256 + threadIdx.x;
    const int4* src = (const int4*)(mask + (size_t)idx * 32);
    unsigned w = 0;
#pragma unroll
    for (int i = 0; i < 8; ++i) {
      int4 v = src[i];
      w |= (v.x != 0 ? 1u : 0u) << (i * 4 + 0);
      w |= (v.y != 0 ? 1u : 0u) << (i * 4 + 1);
      w |= (v.z != 0 ? 1u : 0u) << (i * 4 + 2);
      w |= (v.w != 0 ? 1u : 0u) << (i * 4 + 3);
    }
    mbits[idx] = w;
    return;
  }
  const float* s;
  bf16_t* d;
  int base;
  float sc = 1.0f;
  if (bid < 16384) { s = key; d = I1; base = bid; }
  else if (bid < 32768) { s = query; d = I2; base = bid - 16384; }
  else if (bid < 49152) { s = value; d = I3; base = bid - 32768; }
  else if (bid < 50176) { s = Wk; d = Wkb; base = bid - 49152; }
  else if (bid < 51200) { s = Wq; d = Wqb; base = bid - 50176; sc = QSCALE; }
  else if (bid < 52224) { s = Wv; d = Wvb; base = bid - 51200; }
  else { s = Wp; d = Wpb; base = bid - 52224; }
  int i = base * 256 + threadIdx.x;
  float4 v = ((const float4*)s)[i];
  bf16x4 o;
  o[0] = (bf16_t)(v.x * sc); o[1] = (bf16_t)(v.y * sc);
  o[2] = (bf16_t)(v.z * sc); o[3] = (bf16_t)(v.w * sc);
  ((bf16x4*)d)[i] = o;
}

// ---------------------------------------------------------------------------
// 256x256 tile GEMM (r9-verified): BK=32, 3-buffer ring (96KB dynamic LDS),
// 8 waves (2x4), depth-2 prefetch with counted vmcnt + raw s_barrier.
// bscale multiplies the bias (used to fold QSCALE into the Q projection).
// ---------------------------------------------------------------------------
template <typename OT>
__device__ __forceinline__ void gemm256_body(const bf16_t* __restrict__ A,
                                             const bf16_t* __restrict__ W,
                                             const float* __restrict__ bias,
                                             float bscale,
                                             OT* __restrict__ O) {
  extern __shared__ __align__(16) char smem[];
  bf16_t* AsBase = (bf16_t*)smem;                      // 3 x 256*32
  bf16_t* BsBase = (bf16_t*)(smem + 3 * 8192 * 2);     // 3 x 256*32

  const int t = threadIdx.x;          // 0..511
  const int lane = t & 63;
  const int wid = t >> 6;             // 0..7
  const int g = lane >> 4;            // k-group
  const int lr = lane & 15;
  const int wm = wid >> 2, wn = wid & 3;  // 2 x 4 wave grid
  const int lid = blockIdx.x;
  const int logical = (lid & 7) * 32 + (lid >> 3);
  const int m0 = (logical >> 2) * 256;
  const int n0 = (logical & 3) * 256;

  f32x4 acc[8][4] = {};

  auto STAGE = [&](int buf, int kb) {
    bf16_t* Ab = AsBase + buf * 8192;
    bf16_t* Bb = BsBase + buf * 8192;
#pragma unroll
    for (int rr = 0; rr < 2; ++rr) {
      int s = rr * 512 + t;             // 16B-slot index 0..1023
      int row = s >> 2, c = s & 3;      // tile row, k-chunk
      gl_lds16(A + (size_t)(m0 + row) * 1024 + kb + (c ^ swz2(row)) * 8,
               &Ab[(rr * 512 + wid * 64) * 8]);
      gl_lds16(W + (size_t)(n0 + row) * 1024 + kb + (c ^ swz2(row)) * 8,
               &Bb[(rr * 512 + wid * 64) * 8]);
    }
  };

  STAGE(0, 0);     // tile 0
  STAGE(1, 32);    // tile 1   -> 8 loads outstanding

  int cur = 0;
  for (int kb = 0; kb < 1024; kb += 32) {
    if (kb + 32 < 1024)
      asm volatile("s_waitcnt vmcnt(4)" ::: "memory");
    else
      asm volatile("s_waitcnt vmcnt(0)" ::: "memory");
    __builtin_amdgcn_sched_barrier(0);
    __builtin_amdgcn_s_barrier();     // raw: does NOT drain vmcnt
    __builtin_amdgcn_sched_barrier(0);

    if (kb + 64 < 1024) {
      int fut = cur + 2;
      if (fut >= 3) fut -= 3;
      STAGE(fut, kb + 64);
    }

    const bf16_t* Ab = AsBase + cur * 8192;
    const bf16_t* Bb = BsBase + cur * 8192;
    bf16x8 a[8], b[4];
#pragma unroll
    for (int i = 0; i < 8; ++i) {
      int row = wm * 128 + i * 16 + lr;
      a[i] = *(const bf16x8*)&Ab[row * 32 + ((g ^ swz2(row))) * 8];
    }
#pragma unroll
    for (int j = 0; j < 4; ++j) {
      int row = wn * 64 + j * 16 + lr;
      b[j] = *(const bf16x8*)&Bb[row * 32 + ((g ^ swz2(row))) * 8];
    }
    __builtin_amdgcn_s_setprio(1);
#pragma unroll
    for (int i = 0; i < 8; ++i)
#pragma unroll
      for (int j = 0; j < 4; ++j)
        acc[i][j] = mfma16(a[i], b[j], acc[i][j]);
    __builtin_amdgcn_s_setprio(0);

    cur = (cur == 2) ? 0 : cur + 1;
  }

  float bval[4];
#pragma unroll
  for (int j = 0; j < 4; ++j)
    bval[j] = bias[n0 + wn * 64 + j * 16 + lr] * bscale;
#pragma unroll
  for (int i = 0; i < 8; ++i)
#pragma unroll
    for (int r = 0; r < 4; ++r) {
      int row = m0 + wm * 128 + i * 16 + g * 4 + r;
#pragma unroll
      for (int j = 0; j < 4; ++j) {
        int n = n0 + wn * 64 + j * 16 + lr;
        O[(size_t)row * 1024 + n] = (OT)(acc[i][j][r] + bval[j]);
      }
    }
}

__global__ __launch_bounds__(512, 2) void gemm256_qkv_kernel(
    const bf16_t* key, const bf16_t* query, const bf16_t* value,
    const bf16_t* Wkb, const bf16_t* Wqb, const bf16_t* Wvb, const float* bk,
    const float* bq, const float* bv, bf16_t* ko, bf16_t* qo, bf16_t* vo) {
  const bf16_t *A, *W;
  const float* bi;
  bf16_t* O;
  float bs = 1.0f;
  if (blockIdx.y == 0) { A = key; W = Wkb; bi = bk; O = ko; }
  else if (blockIdx.y == 1) { A = query; W = Wqb; bi = bq; O = qo; bs = QSCALE; }
  else { A = value; W = Wvb; bi = bv; O = vo; }
  gemm256_body<bf16_t>(A, W, bi, bs, O);
}

__global__ __launch_bounds__(512, 2) void gemm256_out_kernel(
    const bf16_t* __restrict__ A, const bf16_t* __restrict__ W,
    const float* __restrict__ b, float* __restrict__ O) {
  gemm256_body<float>(A, W, b, 1.0f, O);
}

// ---------------------------------------------------------------------------
// V transpose: v_ws [b][key][h*64+d] -> vT [(b*16+h)*64 + d][key]
// ---------------------------------------------------------------------------
__global__ __launch_bounds__(256) void transpose_v_kernel(
    const bf16_t* __restrict__ v_ws, bf16_t* __restrict__ vT) {
  __shared__ bf16_t T[64 * 66];
  const int kc = blockIdx.x, h = blockIdx.y, b = blockIdx.z;
  const int t = threadIdx.x;
  {
    int key = t >> 2, dblk = t & 3;
    const bf16_t* src =
        v_ws + ((size_t)(b * 1024 + kc * 64 + key)) * 1024 + h * 64 + dblk * 16;
    bf16x8 a0 = *(const bf16x8*)src;
    bf16x8 a1 = *(const bf16x8*)(src + 8);
    bf16_t* row = &T[key * 66 + dblk * 16];
#pragma unroll
    for (int j = 0; j < 4; ++j) {
      ((unsigned*)row)[j] = ((const unsigned*)&a0)[j];
      ((unsigned*)row)[j + 4] = ((const unsigned*)&a1)[j];
    }
  }
  __syncthreads();
  {
    int d = t >> 2, kcl = t & 3;
    bf16x8 o0, o1;
#pragma unroll
    for (int e = 0; e < 8; ++e) {
      o0[e] = T[(kcl * 16 + e) * 66 + d];
      o1[e] = T[(kcl * 16 + 8 + e) * 66 + d];
    }
    bf16_t* dst =
        vT + ((size_t)((b * 16 + h) * 64 + d)) * 1024 + kc * 64 + kcl * 16;
    *(bf16x8*)dst = o0;
    *(bf16x8*)(dst + 8) = o1;
  }
}

// ---------------------------------------------------------------------------
// Flash attention with 3-slot K/V ring (48KB LDS), counted vmcnt + raw
// s_barrier (r9-GEMM-verified pattern), depth-2 prefetch, mask 2-ahead in regs.
// Ledger/iter: issue {mw:1, STAGE:4}; entry outstanding = 10; vmcnt(5) =>
// tile-t K/V + mask landed, tile-t+1 in flight.
// Softmax: P = exp2(S2), bitwise masking, permlane P-exchange, ones-MFMA l.
// ---------------------------------------------------------------------------
__global__ __launch_bounds__(256) void attn_kernel(
    const bf16_t* __restrict__ q_ws, const bf16_t* __restrict__ k_ws,
    const bf16_t* __restrict__ vT, const unsigned* __restrict__ mbits,
    bf16_t* __restrict__ y_ws) {
  __shared__ __align__(16) bf16_t KsR[3][64 * 64];  // ring: [key][hd] swz
  __shared__ __align__(16) bf16_t VsR[3][64 * 64];  // ring: [d][key] swz

  const int lid = blockIdx.x;                       // 2048 blocks
  const int logical = (lid & 7) * 256 + (lid >> 3); // XCD-contiguous
  const int qb = logical & 7;
  const int h = (logical >> 3) & 15;
  const int b = logical >> 7;
  const int t = threadIdx.x, lane = t & 63, wid = t >> 6;
  const int ql = lane & 31;
  const int hh = lane >> 5;
  const int q = qb * 128 + wid * 32 + ql;

  const bf16_t* Kb = k_ws + ((size_t)b * 1024) * 1024 + h * 64;
  const bf16_t* Vb = vT + ((size_t)((b * 16 + h) * 64)) * 1024;
  const unsigned* mrow = mbits + ((size_t)(b * 1024 + q)) * 32;

  auto STAGE = [&](int buf, int tile) {
#pragma unroll
    for (int rr = 0; rr < 2; ++rr) {
      int s = rr * 256 + t;
      int row = s >> 3, c = s & 7;
      gl_lds16(Kb + (size_t)(tile * 64 + row) * 1024 + (c ^ swz(row)) * 8,
               &KsR[buf][(rr * 256 + wid * 64) * 8]);
      gl_lds16(Vb + (size_t)row * 1024 + tile * 64 + (c ^ swz(row)) * 8,
               &VsR[buf][(rr * 256 + wid * 64) * 8]);
    }
  };

  // Q fragments (Wq pre-scaled by QSCALE in cvt_all -> raw load)
  bf16x8 qf[4];
  {
    const bf16_t* qp = q_ws + ((size_t)(b * 1024 + q)) * 1024 + h * 64 + hh * 8;
#pragma unroll
    for (int kc = 0; kc < 4; ++kc) qf[kc] = *(const bf16x8*)(qp + kc * 16);
  }

  bf16x8 onesf;
#pragma unroll
  for (int e = 0; e < 8; ++e) onesf[e] = (bf16_t)1.0f;

  f32x16 acc0 = {}, acc1 = {}, accl = {};

  // prologue: interleave mask + stage per tile (order matters for the ledger)
  uint2 mw_c = *(const uint2*)&mrow[0];
  STAGE(0, 0);
  uint2 mw_n = *(const uint2*)&mrow[2];
  STAGE(1, 1);
  uint2 mw_f = {0, 0};

  int cur = 0;
  for (int kb = 0; kb < 16; ++kb) {
    if (kb + 1 < 16)
      asm volatile("s_waitcnt vmcnt(5)" ::: "memory");
    else
      asm volatile("s_waitcnt vmcnt(0)" ::: "memory");
    __builtin_amdgcn_sched_barrier(0);
    __builtin_amdgcn_s_barrier();     // raw: does NOT drain vmcnt
    __builtin_amdgcn_sched_barrier(0);

    if (kb + 2 < 16) {
      int fut = cur + 2;
      if (fut >= 3) fut -= 3;
      mw_f = *(const uint2*)&mrow[(kb + 2) * 2];
      STAGE(fut, kb + 2);
    }

    const bf16_t* Ks = KsR[cur];
    const bf16_t* Vs = VsR[cur];

    // ---- QK^T: c0 = keys kb*64..+31, c1 = +32..63; D[row=key][col=q]
    f32x16 c0 = {}, c1 = {};
    __builtin_amdgcn_s_setprio(1);
#pragma unroll
    for (int kc = 0; kc < 4; ++kc) {
      int sl = kc * 2 + hh;
      {
        int row = ql;
        bf16x8 kf = *(const bf16x8*)&Ks[row * 64 + ((sl ^ swz(row))) * 8];
        c0 = mfma32(kf, qf[kc], c0);
      }
      {
        int row = 32 + ql;
        bf16x8 kf = *(const bf16x8*)&Ks[row * 64 + ((sl ^ swz(row))) * 8];
        c1 = mfma32(kf, qf[kc], c1);
      }
    }
    __builtin_amdgcn_s_setprio(0);

    // ---- exp2 + bit masking (uniform scale cancels in /l)
    unsigned wx = mw_c.x >> (4 * hh);
    unsigned wy = mw_c.y >> (4 * hh);
    float p0[16], p1[16];
#pragma unroll
    for (int r = 0; r < 16; ++r) {
      const int posr = (r & 3) + 8 * (r >> 2);   // compile-time
      int n0m = (int)(wx << (31 - posr)) >> 31;  // all-ones if bit set
      int n1m = (int)(wy << (31 - posr)) >> 31;
      float e0 = __builtin_amdgcn_exp2f(c0[r]);
      float e1 = __builtin_amdgcn_exp2f(c1[r]);
      p0[r] = __int_as_float(__float_as_int(e0) & n0m);
      p1[r] = __int_as_float(__float_as_int(e1) & n1m);
    }

    // ---- P -> bf16 pairs; halves exchanged via permlane32_swap
    bf16x8 pb[4];
#pragma unroll
    for (int kc = 0; kc < 4; ++kc) {
      const int base = (kc & 1) * 8;
      unsigned lo0, lo1, hi0, hi1;
      if (kc < 2) {
        union { bf16_t h[2]; unsigned u; } a0, a1, b0, b1;
        a0.h[0] = (bf16_t)p0[base + 0]; a0.h[1] = (bf16_t)p0[base + 1];
        a1.h[0] = (bf16_t)p0[base + 2]; a1.h[1] = (bf16_t)p0[base + 3];
        b0.h[0] = (bf16_t)p0[base + 4]; b0.h[1] = (bf16_t)p0[base + 5];
        b1.h[0] = (bf16_t)p0[base + 6]; b1.h[1] = (bf16_t)p0[base + 7];
        lo0 = a0.u; lo1 = a1.u; hi0 = b0.u; hi1 = b1.u;
      } else {
        union { bf16_t h[2]; unsigned u; } a0, a1, b0, b1;
        a0.h[0] = (bf16_t)p1[base + 0]; a0.h[1] = (bf16_t)p1[base + 1];
        a1.h[0] = (bf16_t)p1[base + 2]; a1.h[1] = (bf16_t)p1[base + 3];
        b0.h[0] = (bf16_t)p1[base + 4]; b0.h[1] = (bf16_t)p1[base + 5];
        b1.h[0] = (bf16_t)p1[base + 6]; b1.h[1] = (bf16_t)p1[base + 7];
        lo0 = a0.u; lo1 = a1.u; hi0 = b0.u; hi1 = b1.u;
      }
      u32x2 s0 = __builtin_amdgcn_permlane32_swap(lo0, hi0, false, false);
      u32x2 s1 = __builtin_amdgcn_permlane32_swap(lo1, hi1, false, false);
      union { unsigned u[4]; bf16x8 v; } pk;
      pk.u[0] = s0.x;
      pk.u[1] = s1.x;
      pk.u[2] = s0.y;
      pk.u[3] = s1.y;
      pb[kc] = pk.v;
    }

    // ---- PV + l-sum (ones-MFMA): D[row=d][col=q]
    __builtin_amdgcn_s_setprio(1);
#pragma unroll
    for (int kc = 0; kc < 4; ++kc) {
      int sl = kc * 2 + hh;
      {
        int row = ql;
        bf16x8 vf = *(const bf16x8*)&Vs[row * 64 + ((sl ^ swz(row))) * 8];
        acc0 = mfma32(vf, pb[kc], acc0);
      }
      {
        int row = 32 + ql;
        bf16x8 vf = *(const bf16x8*)&Vs[row * 64 + ((sl ^ swz(row))) * 8];
        acc1 = mfma32(vf, pb[kc], acc1);
      }
      accl = mfma32(onesf, pb[kc], accl);
    }
    __builtin_amdgcn_s_setprio(0);

    mw_c = mw_n;
    mw_n = mw_f;
    cur = (cur == 2) ? 0 : cur + 1;
  }

  float inv = 1.0f / fmaxf(accl[0], 1e-30f);
  bf16_t* yp = y_ws + ((size_t)(b * 1024 + q)) * 1024 + h * 64;
#pragma unroll
  for (int j = 0; j < 4; ++j) {
    bf16x4 o0, o1;
#pragma unroll
    for (int e = 0; e < 4; ++e) {
      o0[e] = (bf16_t)(acc0[4 * j + e] * inv);
      o1[e] = (bf16_t)(acc1[4 * j + e] * inv);
    }
    *(bf16x4*)&yp[8 * j + 4 * hh] = o0;
    *(bf16x4*)&yp[32 + 8 * j + 4 * hh] = o1;
  }
}

// ---------------------------------------------------------------------------
extern "C" void kernel_launch(void* const* d_in, const int* in_sizes, int n_in,
                              void* d_out, int out_size, void* d_ws,
                              size_t ws_size, hipStream_t stream) {
  (void)in_sizes; (void)n_in; (void)out_size; (void)ws_size;
  const float* key = (const float*)d_in[0];
  const float* value = (const float*)d_in[1];
  const float* query = (const float*)d_in[2];
  const int* mask = (const int*)d_in[3];
  const float* Wk = (const float*)d_in[4];
  const float* bk = (const float*)d_in[5];
  const float* Wq = (const float*)d_in[6];
  const float* bq = (const float*)d_in[7];
  const float* Wv = (const float*)d_in[8];
  const float* bv = (const float*)d_in[9];
  const float* Wp = (const float*)d_in[10];
  const float* bp = (const float*)d_in[11];
  float* out = (float*)d_out;

  char* ws = (char*)d_ws;
  const size_t MB = 1ull << 20;
  unsigned* mbits = (unsigned*)(ws);       // 0..2 MiB
  bf16_t* Wkb = (bf16_t*)(ws + 2 * MB);    // 2 MiB each
  bf16_t* Wqb = (bf16_t*)(ws + 4 * MB);
  bf16_t* Wvb = (bf16_t*)(ws + 6 * MB);
  bf16_t* Wpb = (bf16_t*)(ws + 8 * MB);
  bf16_t* I1 = (bf16_t*)(ws + 10 * MB);    // key bf16   (32 MiB each)
  bf16_t* I2 = (bf16_t*)(ws + 42 * MB);    // query bf16
  bf16_t* I3 = (bf16_t*)(ws + 74 * MB);    // value bf16
  bf16_t* k_ws = (bf16_t*)(ws + 106 * MB);
  bf16_t* q_ws = (bf16_t*)(ws + 138 * MB);
  bf16_t* v_ws = (bf16_t*)(ws + 170 * MB);  // end: 202 MiB
  bf16_t* vT_ws = I1;  // dead after qkv gemm
  bf16_t* y_ws = I2;   // dead after qkv gemm

  const size_t GEMM_LDS = 3 * 8192 * 2 * 2;  // 98304 B = 96 KiB

  cvt_all_kernel<<<55296, 256, 0, stream>>>(key, query, value, Wk, Wq, Wv, Wp,
                                            mask, I1, I2, I3, Wkb, Wqb, Wvb,
                                            Wpb, mbits);
  gemm256_qkv_kernel<<<dim3(256, 3), 512, GEMM_LDS, stream>>>(
      I1, I2, I3, Wkb, Wqb, Wvb, bk, bq, bv, k_ws, q_ws, v_ws);
  transpose_v_kernel<<<dim3(16, 16, 16), 256, 0, stream>>>(v_ws, vT_ws);
  attn_kernel<<<2048, 256, 0, stream>>>(q_ws, k_ws, vT_ws, mbits, y_ws);
  gemm256_out_kernel<<<256, 512, GEMM_LDS, stream>>>(y_ws, Wpb, bp, out);
}

// Round 12
// 341.180 us; speedup vs baseline: 1.0555x; 1.0555x over previous
//
#include <hip/hip_runtime.h>

typedef __bf16 bf16_t;
typedef __bf16 bf16x4 __attribute__((ext_vector_type(4)));
typedef __bf16 bf16x8 __attribute__((ext_vector_type(8)));
typedef float f32x4 __attribute__((ext_vector_type(4)));
typedef float f32x16 __attribute__((ext_vector_type(16)));
typedef unsigned u32x2 __attribute__((ext_vector_type(2)));

#define QSCALE 0.18033688f  // 0.125 * log2(e)

// XOR swizzle of the 16B-slot index within a 128B LDS row (8 slots):
__device__ __forceinline__ int swz(int row) { return (row ^ (row >> 3)) & 7; }
// XOR swizzle for 64B rows (4 slots of 16B):
__device__ __forceinline__ int swz2(int row) { return (row ^ (row >> 2)) & 3; }

__device__ __forceinline__ f32x4 mfma16(bf16x8 a, bf16x8 b, f32x4 c) {
  return __builtin_amdgcn_mfma_f32_16x16x32_bf16(a, b, c, 0, 0, 0);
}
__device__ __forceinline__ f32x16 mfma32(bf16x8 a, bf16x8 b, f32x16 c) {
  return __builtin_amdgcn_mfma_f32_32x32x16_bf16(a, b, c, 0, 0, 0);
}

__device__ __forceinline__ void gl_lds16(const void* g, void* l) {
  __builtin_amdgcn_global_load_lds(
      (const __attribute__((address_space(1))) unsigned int*)g,
      (__attribute__((address_space(3))) unsigned int*)l, 16, 0, 0);
}

// ---------------------------------------------------------------------------
// Fused pre-pass (ONE launch): f32->bf16 for 3 inputs + 4 weights + mask pack.
// Wq is pre-scaled by QSCALE (softmax exp2-space fold).
// ---------------------------------------------------------------------------
__global__ __launch_bounds__(256) void cvt_all_kernel(
    const float* __restrict__ key, const float* __restrict__ query,
    const float* __restrict__ value, const float* __restrict__ Wk,
    const float* __restrict__ Wq, const float* __restrict__ Wv,
    const float* __restrict__ Wp, const int* __restrict__ mask,
    bf16_t* __restrict__ I1, bf16_t* __restrict__ I2, bf16_t* __restrict__ I3,
    bf16_t* __restrict__ Wkb, bf16_t* __restrict__ Wqb,
    bf16_t* __restrict__ Wvb, bf16_t* __restrict__ Wpb,
    unsigned* __restrict__ mbits) {
  const int bid = blockIdx.x;
  if (bid >= 53248) {  // mask pack
    int idx = (bid - 53248) * 256 + threadIdx.x;
    const int4* src = (const int4*)(mask + (size_t)idx * 32);
    unsigned w = 0;
#pragma unroll
    for (int i = 0; i < 8; ++i) {
      int4 v = src[i];
      w |= (v.x != 0 ? 1u : 0u) << (i * 4 + 0);
      w |= (v.y != 0 ? 1u : 0u) << (i * 4 + 1);
      w |= (v.z != 0 ? 1u : 0u) << (i * 4 + 2);
      w |= (v.w != 0 ? 1u : 0u) << (i * 4 + 3);
    }
    mbits[idx] = w;
    return;
  }
  const float* s;
  bf16_t* d;
  int base;
  float sc = 1.0f;
  if (bid < 16384) { s = key; d = I1; base = bid; }
  else if (bid < 32768) { s = query; d = I2; base = bid - 16384; }
  else if (bid < 49152) { s = value; d = I3; base = bid - 32768; }
  else if (bid < 50176) { s = Wk; d = Wkb; base = bid - 49152; }
  else if (bid < 51200) { s = Wq; d = Wqb; base = bid - 50176; sc = QSCALE; }
  else if (bid < 52224) { s = Wv; d = Wvb; base = bid - 51200; }
  else { s = Wp; d = Wpb; base = bid - 52224; }
  int i = base * 256 + threadIdx.x;
  float4 v = ((const float4*)s)[i];
  bf16x4 o;
  o[0] = (bf16_t)(v.x * sc); o[1] = (bf16_t)(v.y * sc);
  o[2] = (bf16_t)(v.z * sc); o[3] = (bf16_t)(v.w * sc);
  ((bf16x4*)d)[i] = o;
}

// ---------------------------------------------------------------------------
// 256x256 tile GEMM (r9-verified): BK=32, 3-buffer ring (96KB dynamic LDS),
// 8 waves (2x4), depth-2 prefetch with counted vmcnt + raw s_barrier.
// bscale multiplies the bias (used to fold QSCALE into the Q projection).
// ---------------------------------------------------------------------------
template <typename OT>
__device__ __forceinline__ void gemm256_body(const bf16_t* __restrict__ A,
                                             const bf16_t* __restrict__ W,
                                             const float* __restrict__ bias,
                                             float bscale,
                                             OT* __restrict__ O) {
  extern __shared__ __align__(16) char smem[];
  bf16_t* AsBase = (bf16_t*)smem;                      // 3 x 256*32
  bf16_t* BsBase = (bf16_t*)(smem + 3 * 8192 * 2);     // 3 x 256*32

  const int t = threadIdx.x;          // 0..511
  const int lane = t & 63;
  const int wid = t >> 6;             // 0..7
  const int g = lane >> 4;            // k-group
  const int lr = lane & 15;
  const int wm = wid >> 2, wn = wid & 3;  // 2 x 4 wave grid
  const int lid = blockIdx.x;
  const int logical = (lid & 7) * 32 + (lid >> 3);
  const int m0 = (logical >> 2) * 256;
  const int n0 = (logical & 3) * 256;

  f32x4 acc[8][4] = {};

  auto STAGE = [&](int buf, int kb) {
    bf16_t* Ab = AsBase + buf * 8192;
    bf16_t* Bb = BsBase + buf * 8192;
#pragma unroll
    for (int rr = 0; rr < 2; ++rr) {
      int s = rr * 512 + t;             // 16B-slot index 0..1023
      int row = s >> 2, c = s & 3;      // tile row, k-chunk
      gl_lds16(A + (size_t)(m0 + row) * 1024 + kb + (c ^ swz2(row)) * 8,
               &Ab[(rr * 512 + wid * 64) * 8]);
      gl_lds16(W + (size_t)(n0 + row) * 1024 + kb + (c ^ swz2(row)) * 8,
               &Bb[(rr * 512 + wid * 64) * 8]);
    }
  };

  STAGE(0, 0);     // tile 0
  STAGE(1, 32);    // tile 1   -> 8 loads outstanding

  int cur = 0;
  for (int kb = 0; kb < 1024; kb += 32) {
    if (kb + 32 < 1024)
      asm volatile("s_waitcnt vmcnt(4)" ::: "memory");
    else
      asm volatile("s_waitcnt vmcnt(0)" ::: "memory");
    __builtin_amdgcn_sched_barrier(0);
    __builtin_amdgcn_s_barrier();     // raw: does NOT drain vmcnt
    __builtin_amdgcn_sched_barrier(0);

    if (kb + 64 < 1024) {
      int fut = cur + 2;
      if (fut >= 3) fut -= 3;
      STAGE(fut, kb + 64);
    }

    const bf16_t* Ab = AsBase + cur * 8192;
    const bf16_t* Bb = BsBase + cur * 8192;
    bf16x8 a[8], b[4];
#pragma unroll
    for (int i = 0; i < 8; ++i) {
      int row = wm * 128 + i * 16 + lr;
      a[i] = *(const bf16x8*)&Ab[row * 32 + ((g ^ swz2(row))) * 8];
    }
#pragma unroll
    for (int j = 0; j < 4; ++j) {
      int row = wn * 64 + j * 16 + lr;
      b[j] = *(const bf16x8*)&Bb[row * 32 + ((g ^ swz2(row))) * 8];
    }
    __builtin_amdgcn_s_setprio(1);
#pragma unroll
    for (int i = 0; i < 8; ++i)
#pragma unroll
      for (int j = 0; j < 4; ++j)
        acc[i][j] = mfma16(a[i], b[j], acc[i][j]);
    __builtin_amdgcn_s_setprio(0);

    cur = (cur == 2) ? 0 : cur + 1;
  }

  float bval[4];
#pragma unroll
  for (int j = 0; j < 4; ++j)
    bval[j] = bias[n0 + wn * 64 + j * 16 + lr] * bscale;
#pragma unroll
  for (int i = 0; i < 8; ++i)
#pragma unroll
    for (int r = 0; r < 4; ++r) {
      int row = m0 + wm * 128 + i * 16 + g * 4 + r;
#pragma unroll
      for (int j = 0; j < 4; ++j) {
        int n = n0 + wn * 64 + j * 16 + lr;
        O[(size_t)row * 1024 + n] = (OT)(acc[i][j][r] + bval[j]);
      }
    }
}

__global__ __launch_bounds__(512, 2) void gemm256_qkv_kernel(
    const bf16_t* key, const bf16_t* query, const bf16_t* value,
    const bf16_t* Wkb, const bf16_t* Wqb, const bf16_t* Wvb, const float* bk,
    const float* bq, const float* bv, bf16_t* ko, bf16_t* qo, bf16_t* vo) {
  const bf16_t *A, *W;
  const float* bi;
  bf16_t* O;
  float bs = 1.0f;
  if (blockIdx.y == 0) { A = key; W = Wkb; bi = bk; O = ko; }
  else if (blockIdx.y == 1) { A = query; W = Wqb; bi = bq; O = qo; bs = QSCALE; }
  else { A = value; W = Wvb; bi = bv; O = vo; }
  gemm256_body<bf16_t>(A, W, bi, bs, O);
}

__global__ __launch_bounds__(512, 2) void gemm256_out_kernel(
    const bf16_t* __restrict__ A, const bf16_t* __restrict__ W,
    const float* __restrict__ b, float* __restrict__ O) {
  gemm256_body<float>(A, W, b, 1.0f, O);
}

// ---------------------------------------------------------------------------
// V transpose: v_ws [b][key][h*64+d] -> vT [(b*16+h)*64 + d][key]
// ---------------------------------------------------------------------------
__global__ __launch_bounds__(256) void transpose_v_kernel(
    const bf16_t* __restrict__ v_ws, bf16_t* __restrict__ vT) {
  __shared__ bf16_t T[64 * 66];
  const int kc = blockIdx.x, h = blockIdx.y, b = blockIdx.z;
  const int t = threadIdx.x;
  {
    int key = t >> 2, dblk = t & 3;
    const bf16_t* src =
        v_ws + ((size_t)(b * 1024 + kc * 64 + key)) * 1024 + h * 64 + dblk * 16;
    bf16x8 a0 = *(const bf16x8*)src;
    bf16x8 a1 = *(const bf16x8*)(src + 8);
    bf16_t* row = &T[key * 66 + dblk * 16];
#pragma unroll
    for (int j = 0; j < 4; ++j) {
      ((unsigned*)row)[j] = ((const unsigned*)&a0)[j];
      ((unsigned*)row)[j + 4] = ((const unsigned*)&a1)[j];
    }
  }
  __syncthreads();
  {
    int d = t >> 2, kcl = t & 3;
    bf16x8 o0, o1;
#pragma unroll
    for (int e = 0; e < 8; ++e) {
      o0[e] = T[(kcl * 16 + e) * 66 + d];
      o1[e] = T[(kcl * 16 + 8 + e) * 66 + d];
    }
    bf16_t* dst =
        vT + ((size_t)((b * 16 + h) * 64 + d)) * 1024 + kc * 64 + kcl * 16;
    *(bf16x8*)dst = o0;
    *(bf16x8*)(dst + 8) = o1;
  }
}

// ---------------------------------------------------------------------------
// Flash attention: KVBLK=128 (8 iters), single-buffer syncthreads staging
// (r10-verified structure), per-32-key c-tile pipeline:
// QK(4 mfma) -> exp2+mask -> pack/permlane -> PV(6 mfma) per tile.
// Ks[128][64] swz; Vs[64][128] swz (8-slot XOR within 16-slot rows).
// Softmax: P = exp2(S2) (uniform scale cancels in /l); ones-MFMA l.
// ---------------------------------------------------------------------------
__global__ __launch_bounds__(256) void attn_kernel(
    const bf16_t* __restrict__ q_ws, const bf16_t* __restrict__ k_ws,
    const bf16_t* __restrict__ vT, const unsigned* __restrict__ mbits,
    bf16_t* __restrict__ y_ws) {
  __shared__ __align__(16) bf16_t Ks[128 * 64];   // [key][hd] swz, 16KB
  __shared__ __align__(16) bf16_t Vs[64 * 128];   // [d][key] swz, 16KB

  const int lid = blockIdx.x;                       // 2048 blocks
  const int logical = (lid & 7) * 256 + (lid >> 3); // XCD-contiguous
  const int qb = logical & 7;
  const int h = (logical >> 3) & 15;
  const int b = logical >> 7;
  const int t = threadIdx.x, lane = t & 63, wid = t >> 6;
  const int ql = lane & 31;
  const int hh = lane >> 5;
  const int q = qb * 128 + wid * 32 + ql;

  // Q fragments (Wq pre-scaled by QSCALE in cvt_all -> raw load)
  bf16x8 qf[4];
  {
    const bf16_t* qp = q_ws + ((size_t)(b * 1024 + q)) * 1024 + h * 64 + hh * 8;
#pragma unroll
    for (int kc = 0; kc < 4; ++kc) qf[kc] = *(const bf16x8*)(qp + kc * 16);
  }

  bf16x8 onesf;
#pragma unroll
  for (int e = 0; e < 8; ++e) onesf[e] = (bf16_t)1.0f;

  f32x16 acc0 = {}, acc1 = {}, accl = {};
  const bf16_t* Kb = k_ws + ((size_t)b * 1024) * 1024 + h * 64;
  const bf16_t* Vb = vT + ((size_t)((b * 16 + h) * 64)) * 1024;
  const unsigned* mrow = mbits + ((size_t)(b * 1024 + q)) * 32;

  for (int kb = 0; kb < 8; ++kb) {
    __syncthreads();  // previous tile fully consumed
    // stage K [128 keys][64 hd]: 1024 slots, 4/thread
#pragma unroll
    for (int rr = 0; rr < 4; ++rr) {
      int s = rr * 256 + t;
      int row = s >> 3, c = s & 7;
      gl_lds16(Kb + (size_t)(kb * 128 + row) * 1024 + (c ^ swz(row)) * 8,
               &Ks[(rr * 256 + wid * 64) * 8]);
    }
    // stage V^T [64 d][128 keys]: 1024 slots (16/row), 4/thread
#pragma unroll
    for (int rr = 0; rr < 4; ++rr) {
      int s = rr * 256 + t;
      int row = s >> 4, c = s & 15;
      gl_lds16(Vb + (size_t)row * 1024 + kb * 128 + ((c ^ swz(row))) * 8,
               &Vs[(rr * 256 + wid * 64) * 8]);
    }
    uint4 mw = *(const uint4*)&mrow[kb * 4];
    __syncthreads();  // staging drained

#pragma unroll
    for (int ct = 0; ct < 4; ++ct) {
      // ---- QK^T: keys kb*128 + ct*32 .. +31; D[row=key][col=q]
      f32x16 c = {};
      __builtin_amdgcn_s_setprio(1);
#pragma unroll
      for (int kc = 0; kc < 4; ++kc) {
        int row = ct * 32 + ql;
        bf16x8 kf = *(const bf16x8*)&Ks[row * 64 + (((kc * 2 + hh) ^ swz(row))) * 8];
        c = mfma32(kf, qf[kc], c);
      }
      __builtin_amdgcn_s_setprio(0);

      // ---- exp2 + bit masking (uniform scale cancels in /l)
      unsigned w = ((const unsigned*)&mw)[ct] >> (4 * hh);
      float p[16];
#pragma unroll
      for (int r = 0; r < 16; ++r) {
        const int posr = (r & 3) + 8 * (r >> 2);  // compile-time
        int nm = (int)(w << (31 - posr)) >> 31;   // all-ones if bit set
        float e0 = __builtin_amdgcn_exp2f(c[r]);
        p[r] = __int_as_float(__float_as_int(e0) & nm);
      }

      // ---- pack + permlane32_swap -> 2 P-fragments (keys ct*32 + j*16 ..)
      bf16x8 pbt[2];
#pragma unroll
      for (int j = 0; j < 2; ++j) {
        const int base = j * 8;
        union { bf16_t h[2]; unsigned u; } a0, a1, b0, b1;
        a0.h[0] = (bf16_t)p[base + 0]; a0.h[1] = (bf16_t)p[base + 1];
        a1.h[0] = (bf16_t)p[base + 2]; a1.h[1] = (bf16_t)p[base + 3];
        b0.h[0] = (bf16_t)p[base + 4]; b0.h[1] = (bf16_t)p[base + 5];
        b1.h[0] = (bf16_t)p[base + 6]; b1.h[1] = (bf16_t)p[base + 7];
        u32x2 s0 = __builtin_amdgcn_permlane32_swap(a0.u, b0.u, false, false);
        u32x2 s1 = __builtin_amdgcn_permlane32_swap(a1.u, b1.u, false, false);
        union { unsigned u[4]; bf16x8 v; } pk;
        pk.u[0] = s0.x;
        pk.u[1] = s1.x;
        pk.u[2] = s0.y;
        pk.u[3] = s1.y;
        pbt[j] = pk.v;
      }

      // ---- PV + l-sum for key-slices 2ct, 2ct+1
      __builtin_amdgcn_s_setprio(1);
#pragma unroll
      for (int j = 0; j < 2; ++j) {
        int sl = (2 * ct + j) * 2 + hh;  // 16B slot within 256B V row
        {
          int row = ql;
          bf16x8 vf = *(const bf16x8*)&Vs[row * 128 + ((sl ^ swz(row))) * 8];
          acc0 = mfma32(vf, pbt[j], acc0);
        }
        {
          int row = 32 + ql;
          bf16x8 vf = *(const bf16x8*)&Vs[row * 128 + ((sl ^ swz(row))) * 8];
          acc1 = mfma32(vf, pbt[j], acc1);
        }
        accl = mfma32(onesf, pbt[j], accl);
      }
      __builtin_amdgcn_s_setprio(0);
    }
  }

  float inv = 1.0f / fmaxf(accl[0], 1e-30f);
  bf16_t* yp = y_ws + ((size_t)(b * 1024 + q)) * 1024 + h * 64;
#pragma unroll
  for (int j = 0; j < 4; ++j) {
    bf16x4 o0, o1;
#pragma unroll
    for (int e = 0; e < 4; ++e) {
      o0[e] = (bf16_t)(acc0[4 * j + e] * inv);
      o1[e] = (bf16_t)(acc1[4 * j + e] * inv);
    }
    *(bf16x4*)&yp[8 * j + 4 * hh] = o0;
    *(bf16x4*)&yp[32 + 8 * j + 4 * hh] = o1;
  }
}

// ---------------------------------------------------------------------------
extern "C" void kernel_launch(void* const* d_in, const int* in_sizes, int n_in,
                              void* d_out, int out_size, void* d_ws,
                              size_t ws_size, hipStream_t stream) {
  (void)in_sizes; (void)n_in; (void)out_size; (void)ws_size;
  const float* key = (const float*)d_in[0];
  const float* value = (const float*)d_in[1];
  const float* query = (const float*)d_in[2];
  const int* mask = (const int*)d_in[3];
  const float* Wk = (const float*)d_in[4];
  const float* bk = (const float*)d_in[5];
  const float* Wq = (const float*)d_in[6];
  const float* bq = (const float*)d_in[7];
  const float* Wv = (const float*)d_in[8];
  const float* bv = (const float*)d_in[9];
  const float* Wp = (const float*)d_in[10];
  const float* bp = (const float*)d_in[11];
  float* out = (float*)d_out;

  char* ws = (char*)d_ws;
  const size_t MB = 1ull << 20;
  unsigned* mbits = (unsigned*)(ws);       // 0..2 MiB
  bf16_t* Wkb = (bf16_t*)(ws + 2 * MB);    // 2 MiB each
  bf16_t* Wqb = (bf16_t*)(ws + 4 * MB);
  bf16_t* Wvb = (bf16_t*)(ws + 6 * MB);
  bf16_t* Wpb = (bf16_t*)(ws + 8 * MB);
  bf16_t* I1 = (bf16_t*)(ws + 10 * MB);    // key bf16   (32 MiB each)
  bf16_t* I2 = (bf16_t*)(ws + 42 * MB);    // query bf16
  bf16_t* I3 = (bf16_t*)(ws + 74 * MB);    // value bf16
  bf16_t* k_ws = (bf16_t*)(ws + 106 * MB);
  bf16_t* q_ws = (bf16_t*)(ws + 138 * MB);
  bf16_t* v_ws = (bf16_t*)(ws + 170 * MB);  // end: 202 MiB
  bf16_t* vT_ws = I1;  // dead after qkv gemm
  bf16_t* y_ws = I2;   // dead after qkv gemm

  const size_t GEMM_LDS = 3 * 8192 * 2 * 2;  // 98304 B = 96 KiB

  cvt_all_kernel<<<55296, 256, 0, stream>>>(key, query, value, Wk, Wq, Wv, Wp,
                                            mask, I1, I2, I3, Wkb, Wqb, Wvb,
                                            Wpb, mbits);
  gemm256_qkv_kernel<<<dim3(256, 3), 512, GEMM_LDS, stream>>>(
      I1, I2, I3, Wkb, Wqb, Wvb, bk, bq, bv, k_ws, q_ws, v_ws);
  transpose_v_kernel<<<dim3(16, 16, 16), 256, 0, stream>>>(v_ws, vT_ws);
  attn_kernel<<<2048, 256, 0, stream>>>(q_ws, k_ws, vT_ws, mbits, y_ws);
  gemm256_out_kernel<<<256, 512, GEMM_LDS, stream>>>(y_ws, Wpb, bp, out);
}